// Round 11
// baseline (863.634 us; speedup 1.0000x reference)
//
#include <hip/hip_runtime.h>
#include <hip/hip_bf16.h>

#define E_EDGES 1000000
#define N_NODES 100000

typedef __attribute__((ext_vector_type(8))) short bf16x8;
typedef __attribute__((ext_vector_type(4))) float f32x4;

#define WAITV(N) asm volatile("s_waitcnt vmcnt(" #N ")" ::: "memory")
#define WAITL()  asm volatile("s_waitcnt lgkmcnt(0)" ::: "memory")
#define BAR()    __builtin_amdgcn_s_barrier()

__device__ __forceinline__ short f2bf(float f) {
    union { __bf16 b; short s; } u;
    u.b = (__bf16)f;
    return u.s;
}
__device__ __forceinline__ bf16x8 pack8(float4 a, float4 b) {
    bf16x8 r;
    r[0]=f2bf(a.x); r[1]=f2bf(a.y); r[2]=f2bf(a.z); r[3]=f2bf(a.w);
    r[4]=f2bf(b.x); r[5]=f2bf(b.y); r[6]=f2bf(b.z); r[7]=f2bf(b.w);
    return r;
}
__device__ __forceinline__ float4 ld4(const float* p) {
    return *reinterpret_cast<const float4*>(p);
}
__device__ __forceinline__ float silu1(float x) { return x / (1.f + __expf(-x)); }
__device__ __forceinline__ float tanh1(float x) {
    float e = __expf(2.f * x);
    return 1.f - 2.f / (e + 1.f);
}

// ---------------- weight pre-pack: f32 -> bf16 frags in CHUNK-LINEAR order ------
__global__ void pack_weights_kernel(const float* __restrict__ Wt,
                                    const float* __restrict__ Win,
                                    const float* __restrict__ W1,
                                    const float* __restrict__ W2,
                                    short* __restrict__ ws)
{
    int gid = blockIdx.x * 256 + threadIdx.x;
    if (gid >= 196 * 512) return;
    int frag = gid >> 9, within = gid & 511;
    int l = within >> 3, j = within & 7;
    int lg = l >> 4, ln = l & 15;
    int krow = (lg << 3) + j;
    float v;
    if (frag < 96) {
        int cs = frag >> 3, nt = frag & 7;
        int seg = cs >> 2, ks = cs & 3;
        int k = seg * 128 + ks * 32 + krow;
        v = Win[k * 128 + nt * 16 + ln];
    } else if (frag < 160) {
        int t = frag - 96, ch = t >> 3, sub = t & 7;
        int jj = sub >> 2, ks = sub & 3;
        int jcol = (ch < 4) ? (8 + 2 * ch + jj) : (2 * (ch - 4) + jj);
        int k = ks * 32 + krow;
        v = Wt[k * 256 + jcol * 16 + ln];
    } else if (frag < 192) {
        int t = frag - 160, ch = t >> 3, sub = t & 7;
        int nt = 2 * ch + (sub >> 2), ks = sub & 3;
        int k = ks * 32 + krow;
        v = W1[k * 128 + nt * 16 + ln];
    } else {
        int ks = frag - 192;
        int k = ks * 32 + krow;
        v = (ln < 4) ? W2[k * 4 + ln] : 0.0f;
    }
    ws[gid] = f2bf(v);
}

// ---------------- h -> bf16 table (one streaming pass) -------------------------
__global__ void h_pack_kernel(const float* __restrict__ h, short* __restrict__ hbf) {
    long i = (long)(blockIdx.x * 256 + threadIdx.x) * 8;
    if (i >= (long)N_NODES * 128) return;
    float4 a = ld4(h + i), b = ld4(h + i + 4);
    *reinterpret_cast<bf16x8*>(hbf + i) = pack8(a, b);
}

__device__ __forceinline__ void stage_frag(const short* gsrc, short* ldst) {
    __builtin_amdgcn_global_load_lds(
        (const __attribute__((address_space(1))) void*)gsrc,
        (__attribute__((address_space(3))) void*)ldst, 16, 0, 0);
}

// swizzled transpose index (shorts) within a per-wave 16x64 slice
__device__ __forceinline__ int tswz(int row, int colS) {
    return (row * 64 + colS) ^ ((row & 7) << 3);
}

// ------ fused edge kernel: 4 waves x 16 edges; depth-3 shared chunk rotation;
//        transposes reuse idle Wb[1] slice -> LDS 24576 B -> 6 blocks/CU ------
template<bool HBF>
__global__ __launch_bounds__(256, 6)
void edge_kernel(const float* __restrict__ h,
                 const short* __restrict__ hbf,
                 const float* __restrict__ pos,
                 const float* __restrict__ ea,
                 const float* __restrict__ dst_f,
                 const float* __restrict__ temb,
                 const float* __restrict__ adj,
                 const float* __restrict__ btime,
                 const float* __restrict__ bin,
                 const float* __restrict__ b1,
                 const float* __restrict__ cscale,
                 const int*   __restrict__ ei,
                 const short* __restrict__ ws,
                 float* __restrict__ out)
{
    __shared__ __align__(16) short Wb[3][4096];   // 3 x 8 KB rotating weight chunks (24 KB total)

    const int tid = threadIdx.x;
    const int w   = tid >> 6;
    const int l   = tid & 63;
    const int ln  = l & 15;
    const int lg  = l >> 4;
    const int kb  = lg << 3;
    const int e0w = blockIdx.x * 64 + w * 16;
    const int em  = e0w + ln;                // this lane's edge (1 tile/wave)

    const int ir = ei[em];
    const int ic = ei[E_EDGES + em];

    // geometry raw loads (math deferred to epilogue)
    const float px0 = pos[ir*3+0], py0 = pos[ir*3+1], pz0 = pos[ir*3+2];
    const float px1 = pos[ic*3+0], py1 = pos[ic*3+1], pz1 = pos[ic*3+2];
    const float a0  = adj[em*3+0], a1  = adj[em*3+1], a2  = adj[em*3+2];
    const float csc = cscale[0];

    // bias preloads -> registers (no VMEM in later phases)
    float btsh[8], btsc[8], binr[8], b1r[8];
    #pragma unroll
    for (int j = 0; j < 8; ++j) {
        btsh[j] = btime[(j<<4) + ln];
        btsc[j] = btime[128 + (j<<4) + ln];
        binr[j] = bin[(j<<4) + ln];
        b1r[j]  = b1[(j<<4) + ln];
    }

    #define STAGE8(p) { \
        const short* g_ = ws + (p) * 4096 + (w*2) * 512 + l * 8; \
        short* d_ = &Wb[(p) % 3][(w*2) * 512]; \
        stage_frag(g_, d_); \
        stage_frag(g_ + 512, d_ + 512); }
    #define STAGEW2() { \
        stage_frag(ws + 24 * 4096 + w * 512 + l * 8, &Wb[0][w * 512]); }

    // ---- prologue: seg0 A, then chunks 0 and 1 ----
    float4 Abuf[8];
    bf16x8 afb[4], afn[4];
    if (HBF) {
        #pragma unroll
        for (int k2 = 0; k2 < 4; ++k2)
            afb[k2] = *reinterpret_cast<const bf16x8*>(hbf + (long)ir * 128 + k2*32 + kb);
    } else {
        #pragma unroll
        for (int k2 = 0; k2 < 4; ++k2) {
            Abuf[2*k2]   = ld4(h + (long)ir * 128 + k2*32 + kb);
            Abuf[2*k2+1] = ld4(h + (long)ir * 128 + k2*32 + kb + 4);
        }
    }
    STAGE8(0);
    STAGE8(1);

    f32x4 accX[8];
    #pragma unroll
    for (int i = 0; i < 8; ++i) accX[i] = (f32x4){0.f,0.f,0.f,0.f};

    // ---- X = h_input @ W_in : chunks 0..11 ----
    #pragma unroll
    for (int c = 0; c < 12; ++c) {
        if (HBF) {
            if      (c == 2 || c == 3)                         { WAITV(6);  }
            else if (c == 6 || c == 7 || c == 10 || c == 11)   { WAITV(10); }
            else                                               { WAITV(2);  }
        } else {
            if (c==2||c==3||c==6||c==7||c==10||c==11)          { WAITV(10); }
            else                                               { WAITV(2);  }
        }
        BAR();                                   // chunk c visible; buf (c+2)%3 free
        STAGE8(c + 2);                           // chunks 2..13
        if (c == 1) {            // seg1: h[col]
            if (HBF) {
                #pragma unroll
                for (int k2 = 0; k2 < 4; ++k2)
                    afn[k2] = *reinterpret_cast<const bf16x8*>(hbf + (long)ic * 128 + k2*32 + kb);
            } else {
                #pragma unroll
                for (int k2 = 0; k2 < 4; ++k2) {
                    Abuf[2*k2]   = ld4(h + (long)ic * 128 + k2*32 + kb);
                    Abuf[2*k2+1] = ld4(h + (long)ic * 128 + k2*32 + kb + 4);
                }
            }
        }
        if (c == 5) {            // seg2: ea | dist (f32 always)
            #pragma unroll
            for (int k2 = 0; k2 < 4; ++k2) {
                const float* q = (k2 < 2) ? (ea    + (long)em*64 + k2*32 + kb)
                                          : (dst_f + (long)em*64 + (k2-2)*32 + kb);
                Abuf[2*k2]   = ld4(q);
                Abuf[2*k2+1] = ld4(q + 4);
            }
        }
        if (c == 9) {            // temb rows for T stage
            #pragma unroll
            for (int k2 = 0; k2 < 4; ++k2) {
                Abuf[2*k2]   = ld4(temb + (long)em * 128 + k2*32 + kb);
                Abuf[2*k2+1] = ld4(temb + (long)em * 128 + k2*32 + kb + 4);
            }
        }
        if (!HBF && (c == 0 || c == 4)) {        // pack seg0/seg1 from Abuf
            #pragma unroll
            for (int k2 = 0; k2 < 4; ++k2) afb[k2] = pack8(Abuf[2*k2], Abuf[2*k2+1]);
        }
        if (c == 8) {                            // pack seg2 from Abuf (both paths)
            #pragma unroll
            for (int k2 = 0; k2 < 4; ++k2) afb[k2] = pack8(Abuf[2*k2], Abuf[2*k2+1]);
        }
        {
            const int ks = c & 3;
            const bf16x8 a_use = (HBF && c >= 4 && c < 8) ? afn[ks] : afb[ks];
            const short* wb = &Wb[c % 3][0];
            #pragma unroll
            for (int nt = 0; nt < 8; ++nt) {
                bf16x8 b = *reinterpret_cast<const bf16x8*>(&wb[nt*512 + l*8]);
                accX[nt] = __builtin_amdgcn_mfma_f32_16x16x32_bf16(a_use, b, accX[nt], 0, 0, 0);
            }
        }
    }

    // ---- bias + LayerNorm (register-only; chunks 12,13 in flight) ----
    #pragma unroll
    for (int nt = 0; nt < 8; ++nt) {
        #pragma unroll
        for (int r = 0; r < 4; ++r) accX[nt][r] += binr[nt];
    }
    #pragma unroll
    for (int r = 0; r < 4; ++r) {
        float p = 0.f, q = 0.f;
        #pragma unroll
        for (int nt = 0; nt < 8; ++nt) { float x = accX[nt][r]; p += x; q += x*x; }
        #pragma unroll
        for (int d2 = 1; d2 < 16; d2 <<= 1) { p += __shfl_xor(p, d2); q += __shfl_xor(q, d2); }
        float mean = p * 0.0078125f;
        float var  = q * 0.0078125f - mean * mean;
        float rstd = rsqrtf(var + 1e-6f);
        #pragma unroll
        for (int nt = 0; nt < 8; ++nt)
            accX[nt][r] = (accX[nt][r] - mean) * rstd;
    }

    // ---- silu(temb) fragments from Abuf ----
    bf16x8 ttf[4];
    #pragma unroll
    for (int k2 = 0; k2 < 4; ++k2) {
        float4 va = Abuf[2*k2], vb = Abuf[2*k2+1];
        va.x=silu1(va.x); va.y=silu1(va.y); va.z=silu1(va.z); va.w=silu1(va.w);
        vb.x=silu1(vb.x); vb.y=silu1(vb.y); vb.z=silu1(vb.z); vb.w=silu1(vb.w);
        ttf[k2] = pack8(va, vb);
    }

    // ---- T stage: chunks 12..19, FiLM inline ----
    #pragma unroll
    for (int t = 0; t < 8; ++t) {
        WAITV(2);
        BAR();
        STAGE8(14 + t);                          // chunks 14..21
        {
            const short* wb = &Wb[(12 + t) % 3][0];
            #pragma unroll
            for (int jj = 0; jj < 2; ++jj) {
                f32x4 tt = (f32x4){0.f,0.f,0.f,0.f};
                #pragma unroll
                for (int ks = 0; ks < 4; ++ks) {
                    bf16x8 b = *reinterpret_cast<const bf16x8*>(&wb[(jj*4+ks)*512 + l*8]);
                    tt = __builtin_amdgcn_mfma_f32_16x16x32_bf16(ttf[ks], b, tt, 0, 0, 0);
                }
                if (t < 4) {
                    const int jx = 2*t + jj;
                    #pragma unroll
                    for (int r = 0; r < 4; ++r) accX[jx][r] *= (1.f + tt[r] + btsc[jx]);
                } else {
                    const int jx = 2*(t-4) + jj;
                    #pragma unroll
                    for (int r = 0; r < 4; ++r) accX[jx][r] += tt[r] + btsh[jx];
                }
            }
        }
    }

    // ---- transpose inv -> A-layout, reusing idle Wb[1] (chunk 19 consumed,
    //      not restaged until chunk 22). lgkmcnt(0)+BAR guards the reuse. ----
    short* tbW = &Wb[1][w * 1024];
    bf16x8 iaf[4];
    WAITL();                                     // own buf-1 reads (t=7) complete
    BAR();                                       // all waves done with chunk 19
    #pragma unroll
    for (int hp = 0; hp < 2; ++hp) {
        #pragma unroll
        for (int nt4 = 0; nt4 < 4; ++nt4) {
            const int nt = hp*4 + nt4;
            #pragma unroll
            for (int r = 0; r < 4; ++r)
                tbW[tswz((lg<<2) + r, (nt4<<4) + ln)] = f2bf(accX[nt][r]);
        }
        #pragma unroll
        for (int k2 = 0; k2 < 2; ++k2)
            iaf[hp*2 + k2] = *reinterpret_cast<const bf16x8*>(&tbW[tswz(ln, (k2<<5) + kb)]);
    }
    WAITL();                                     // transpose reads complete before
                                                 // stage(22) can overwrite buf 1

    // ---- W1 stage: chunks 20..23 ----
    f32x4 accY[8];
    #pragma unroll
    for (int i = 0; i < 8; ++i) accY[i] = (f32x4){0.f,0.f,0.f,0.f};
    #pragma unroll
    for (int u = 0; u < 4; ++u) {
        if (u < 3) { WAITV(2); } else { WAITV(1); }
        BAR();
        if (u < 2)       { STAGE8(22 + u); }     // chunks 22, 23
        else if (u == 2) { STAGEW2(); }          // chunk 24 (1 op/wave)
        {
            const short* wb = &Wb[(20 + u) % 3][0];
            #pragma unroll
            for (int s = 0; s < 2; ++s) {
                const int nt = 2*u + s;
                #pragma unroll
                for (int ks = 0; ks < 4; ++ks) {
                    bf16x8 b = *reinterpret_cast<const bf16x8*>(&wb[(s*4+ks)*512 + l*8]);
                    accY[nt] = __builtin_amdgcn_mfma_f32_16x16x32_bf16(iaf[ks], b, accY[nt], 0, 0, 0);
                }
            }
        }
    }

    // ---- silu + transpose back, reusing Wb[1] again (chunk 22 consumed,
    //      never restaged) ----
    bf16x8 yaf[4];
    WAITL();
    BAR();
    #pragma unroll
    for (int hp = 0; hp < 2; ++hp) {
        #pragma unroll
        for (int nt4 = 0; nt4 < 4; ++nt4) {
            const int nt = hp*4 + nt4;
            #pragma unroll
            for (int r = 0; r < 4; ++r)
                tbW[tswz((lg<<2) + r, (nt4<<4) + ln)] = f2bf(silu1(accY[nt][r] + b1r[nt]));
        }
        #pragma unroll
        for (int k2 = 0; k2 < 2; ++k2)
            yaf[hp*2 + k2] = *reinterpret_cast<const bf16x8*>(&tbW[tswz(ln, (k2<<5) + kb)]);
    }

    // ---- W2 stage (chunk 24, buf 0) ----
    WAITV(0);
    BAR();
    f32x4 accZ = (f32x4){0.f,0.f,0.f,0.f};
    {
        const short* wb = &Wb[0][0];
        #pragma unroll
        for (int ks = 0; ks < 4; ++ks) {
            bf16x8 b = *reinterpret_cast<const bf16x8*>(&wb[ks*512 + l*8]);
            accZ = __builtin_amdgcn_mfma_f32_16x16x32_bf16(yaf[ks], b, accZ, 0, 0, 0);
        }
    }

    // ---- epilogue: geometry math + tanh + head-mean + atomic scatter ----
    {
        float dx = px0 - px1, dy = py0 - py1, dz = pz0 - pz1;
        float nrm = sqrtf(dx*dx + dy*dy + dz*dz);
        float sc  = csc / fmaxf(nrm, 1e-8f);
        float cdx = dx * sc, cdy = dy * sc, cdz = dz * sc;
        #pragma unroll
        for (int r = 0; r < 4; ++r) {
            const int m = (lg<<2) + r;           // edge within the wave tile
            float z  = tanh1(accZ[r]);
            float w0 = __shfl(a0, m), w1 = __shfl(a1, m), w2 = __shfl(a2, m);
            int   irm  = __shfl(ir, m);
            float cdxm = __shfl(cdx, m), cdym = __shfl(cdy, m), cdzm = __shfl(cdz, m);
            float wt = (ln == 0) ? 1.0f : (ln == 1 ? w0 : (ln == 2 ? w1 : (ln == 3 ? w2 : 0.0f)));
            float v = z * wt;
            v += __shfl_xor(v, 1);
            v += __shfl_xor(v, 2);               // heads 0..3 summed within 4-lane group
            float s = v * 0.25f;
            if (ln < 3) {
                float cdc = (ln == 0) ? cdxm : (ln == 1 ? cdym : cdzm);
                atomicAdd(&out[(long)irm*3 + ln], cdc * s);
            }
        }
    }
    #undef STAGE8
    #undef STAGEW2
}

extern "C" void kernel_launch(void* const* d_in, const int* in_sizes, int n_in,
                              void* d_out, int out_size, void* d_ws, size_t ws_size,
                              hipStream_t stream) {
    const float* h     = (const float*)d_in[0];
    const float* pos   = (const float*)d_in[1];
    const float* ea    = (const float*)d_in[2];
    const float* dist  = (const float*)d_in[3];
    const float* temb  = (const float*)d_in[4];
    const float* adj   = (const float*)d_in[5];
    const float* Wt    = (const float*)d_in[6];
    const float* bt    = (const float*)d_in[7];
    const float* Win   = (const float*)d_in[8];
    const float* bin   = (const float*)d_in[9];
    const float* W1    = (const float*)d_in[10];
    const float* b1    = (const float*)d_in[11];
    const float* W2    = (const float*)d_in[12];
    const float* cs    = (const float*)d_in[13];
    const int*   ei    = (const int*)d_in[14];
    float*       out   = (float*)d_out;
    short*       ws    = (short*)d_ws;

    const size_t W_SHORTS  = 25 * 4096;                       // 102400
    const size_t H_SHORTS  = (size_t)N_NODES * 128;           // 12.8M
    const bool   use_hbf   = ws_size >= (W_SHORTS + H_SHORTS) * sizeof(short);
    short*       hbf       = ws + W_SHORTS;

    pack_weights_kernel<<<(196*512 + 255) / 256, 256, 0, stream>>>(Wt, Win, W1, W2, ws);
    if (use_hbf)
        h_pack_kernel<<<(int)(H_SHORTS / 8 / 256), 256, 0, stream>>>(h, hbf);
    hipMemcpyAsync(out, pos, (size_t)out_size * sizeof(float),
                   hipMemcpyDeviceToDevice, stream);
    if (use_hbf)
        edge_kernel<true><<<E_EDGES / 64, 256, 0, stream>>>(h, hbf, pos, ea, dist, temb, adj,
                                                            bt, bin, b1, cs, ei, ws, out);
    else
        edge_kernel<false><<<E_EDGES / 64, 256, 0, stream>>>(h, hbf, pos, ea, dist, temb, adj,
                                                             bt, bin, b1, cs, ei, ws, out);
}

// Round 12
// 716.359 us; speedup vs baseline: 1.2056x; 1.2056x over previous
//
#include <hip/hip_runtime.h>
#include <hip/hip_bf16.h>

#define E_EDGES 1000000
#define N_NODES 100000

typedef __attribute__((ext_vector_type(8))) short bf16x8;
typedef __attribute__((ext_vector_type(4))) float f32x4;

#define WAITV(N) asm volatile("s_waitcnt vmcnt(" #N ")" ::: "memory")
#define WAITL()  asm volatile("s_waitcnt lgkmcnt(0)" ::: "memory")
#define BAR()    __builtin_amdgcn_s_barrier()

__device__ __forceinline__ short f2bf(float f) {
    union { __bf16 b; short s; } u;
    u.b = (__bf16)f;
    return u.s;
}
__device__ __forceinline__ bf16x8 pack8(float4 a, float4 b) {
    bf16x8 r;
    r[0]=f2bf(a.x); r[1]=f2bf(a.y); r[2]=f2bf(a.z); r[3]=f2bf(a.w);
    r[4]=f2bf(b.x); r[5]=f2bf(b.y); r[6]=f2bf(b.z); r[7]=f2bf(b.w);
    return r;
}
__device__ __forceinline__ float4 ld4(const float* p) {
    return *reinterpret_cast<const float4*>(p);
}
__device__ __forceinline__ float silu1(float x) { return x / (1.f + __expf(-x)); }
__device__ __forceinline__ float tanh1(float x) {
    float e = __expf(2.f * x);
    return 1.f - 2.f / (e + 1.f);
}

// ---------------- weight pre-pack: f32 -> bf16 frags in CHUNK-LINEAR order ------
__global__ void pack_weights_kernel(const float* __restrict__ Wt,
                                    const float* __restrict__ Win,
                                    const float* __restrict__ W1,
                                    const float* __restrict__ W2,
                                    short* __restrict__ ws)
{
    int gid = blockIdx.x * 256 + threadIdx.x;
    if (gid >= 196 * 512) return;
    int frag = gid >> 9, within = gid & 511;
    int l = within >> 3, j = within & 7;
    int lg = l >> 4, ln = l & 15;
    int krow = (lg << 3) + j;
    float v;
    if (frag < 96) {
        int cs = frag >> 3, nt = frag & 7;
        int seg = cs >> 2, ks = cs & 3;
        int k = seg * 128 + ks * 32 + krow;
        v = Win[k * 128 + nt * 16 + ln];
    } else if (frag < 160) {
        int t = frag - 96, ch = t >> 3, sub = t & 7;
        int jj = sub >> 2, ks = sub & 3;
        int jcol = (ch < 4) ? (8 + 2 * ch + jj) : (2 * (ch - 4) + jj);
        int k = ks * 32 + krow;
        v = Wt[k * 256 + jcol * 16 + ln];
    } else if (frag < 192) {
        int t = frag - 160, ch = t >> 3, sub = t & 7;
        int nt = 2 * ch + (sub >> 2), ks = sub & 3;
        int k = ks * 32 + krow;
        v = W1[k * 128 + nt * 16 + ln];
    } else {
        int ks = frag - 192;
        int k = ks * 32 + krow;
        v = (ln < 4) ? W2[k * 4 + ln] : 0.0f;
    }
    ws[gid] = f2bf(v);
}

// ---------------- h -> bf16 table (one streaming pass) -------------------------
__global__ void h_pack_kernel(const float* __restrict__ h, short* __restrict__ hbf) {
    long i = (long)(blockIdx.x * 256 + threadIdx.x) * 8;
    if (i >= (long)N_NODES * 128) return;
    float4 a = ld4(h + i), b = ld4(h + i + 4);
    *reinterpret_cast<bf16x8*>(hbf + i) = pack8(a, b);
}

__device__ __forceinline__ void stage_frag(const short* gsrc, short* ldst) {
    __builtin_amdgcn_global_load_lds(
        (const __attribute__((address_space(1))) void*)gsrc,
        (__attribute__((address_space(3))) void*)ldst, 16, 0, 0);
}

// swizzled transpose index (shorts) within a per-wave 16x64 slice
__device__ __forceinline__ int tswz(int row, int colS) {
    return (row * 64 + colS) ^ ((row & 7) << 3);
}

// ------ fused edge kernel: 4 waves x 32 edges (jam-2); shared depth-3 rotation;
//        biases in LDS; geometry deferred; transposes reuse idle Wb[1] ------
template<bool HBF>
__global__ __launch_bounds__(256, 3)
void edge_kernel(const float* __restrict__ h,
                 const short* __restrict__ hbf,
                 const float* __restrict__ pos,
                 const float* __restrict__ ea,
                 const float* __restrict__ dst_f,
                 const float* __restrict__ temb,
                 const float* __restrict__ adj,
                 const float* __restrict__ btime,
                 const float* __restrict__ bin,
                 const float* __restrict__ b1,
                 const float* __restrict__ cscale,
                 const int*   __restrict__ ei,
                 const short* __restrict__ ws,
                 float* __restrict__ out)
{
    __shared__ __align__(16) short Wb[3][4096];   // 3 x 8 KB rotating weight chunks
    __shared__ float sBias[512];                  // [0:128) bin, [128:256) b1,
                                                  // [256:384) bt_shift, [384:512) bt_scale

    const int tid = threadIdx.x;
    const int w   = tid >> 6;
    const int l   = tid & 63;
    const int ln  = l & 15;
    const int lg  = l >> 4;
    const int kb  = lg << 3;
    const int e0w = blockIdx.x * 128 + w * 32;
    const int em0 = e0w + ln;
    const int em1 = e0w + 16 + ln;
    const int em0c = min(em0, E_EDGES - 1);
    const int em1c = min(em1, E_EDGES - 1);

    const int ir0 = ei[em0c], ir1 = ei[em1c];
    const int ic0 = ei[E_EDGES + em0c], ic1 = ei[E_EDGES + em1c];

    // biases -> LDS (issued before any stage op: older in vmcnt order)
    #pragma unroll
    for (int i = 0; i < 2; ++i) {
        int idx = tid + i * 256;
        float v = (idx < 128) ? bin[idx] : (idx < 256) ? b1[idx - 128] : btime[idx - 256];
        sBias[idx] = v;
    }
    WAITL();   // ds_writes retired before first barrier

    #define STAGE8(p) { \
        const short* g_ = ws + (p) * 4096 + (w*2) * 512 + l * 8; \
        short* d_ = &Wb[(p) % 3][(w*2) * 512]; \
        stage_frag(g_, d_); \
        stage_frag(g_ + 512, d_ + 512); }
    #define STAGEW2() { \
        stage_frag(ws + 24 * 4096 + w * 512 + l * 8, &Wb[0][w * 512]); }

    // ---- prologue: seg0 A fragments (both tiles), chunks 0,1 ----
    bf16x8 s0f0[4], s0f1[4], s1f0[4], s1f1[4], s2f0[4], s2f1[4], ttf0[4], ttf1[4];
    float4 tf[8];                       // time-shared f32 staging (one tile at a time)
    if (HBF) {
        #pragma unroll
        for (int k2 = 0; k2 < 4; ++k2) {
            s0f0[k2] = *reinterpret_cast<const bf16x8*>(hbf + (long)ir0 * 128 + k2*32 + kb);
            s0f1[k2] = *reinterpret_cast<const bf16x8*>(hbf + (long)ir1 * 128 + k2*32 + kb);
        }
    } else {
        #pragma unroll
        for (int k2 = 0; k2 < 4; ++k2) {
            s0f0[k2] = pack8(ld4(h + (long)ir0*128 + k2*32 + kb), ld4(h + (long)ir0*128 + k2*32 + kb + 4));
            s0f1[k2] = pack8(ld4(h + (long)ir1*128 + k2*32 + kb), ld4(h + (long)ir1*128 + k2*32 + kb + 4));
        }
    }
    STAGE8(0);
    STAGE8(1);

    f32x4 accX0[8], accX1[8];
    #pragma unroll
    for (int i = 0; i < 8; ++i) {
        accX0[i] = (f32x4){0.f,0.f,0.f,0.f};
        accX1[i] = (f32x4){0.f,0.f,0.f,0.f};
    }

    // ---- X = h_input @ W_in : chunks 0..11 (16 MFMA each) ----
    #pragma unroll
    for (int c = 0; c < 12; ++c) {
        // ledger: 2 stage ops/chunk; 8-op A batches at c in {1,4,6,8,10}
        if (c==2||c==3||c==5||c==6||c==7||c==8||c==9||c==10||c==11) { WAITV(10); }
        else { WAITV(2); }
        BAR();                                   // chunk c visible; buf (c+2)%3 free
        STAGE8(c + 2);                           // chunks 2..13
        if (c == 1) {            // seg1: h[col] (both tiles)
            if (HBF) {
                #pragma unroll
                for (int k2 = 0; k2 < 4; ++k2) {
                    s1f0[k2] = *reinterpret_cast<const bf16x8*>(hbf + (long)ic0 * 128 + k2*32 + kb);
                    s1f1[k2] = *reinterpret_cast<const bf16x8*>(hbf + (long)ic1 * 128 + k2*32 + kb);
                }
            } else {
                #pragma unroll
                for (int k2 = 0; k2 < 4; ++k2) {
                    s1f0[k2] = pack8(ld4(h + (long)ic0*128 + k2*32 + kb), ld4(h + (long)ic0*128 + k2*32 + kb + 4));
                    s1f1[k2] = pack8(ld4(h + (long)ic1*128 + k2*32 + kb), ld4(h + (long)ic1*128 + k2*32 + kb + 4));
                }
            }
        }
        if (c == 4) {            // seg2 tile0 f32 loads -> tf
            #pragma unroll
            for (int k2 = 0; k2 < 4; ++k2) {
                const float* q = (k2 < 2) ? (ea    + (long)em0c*64 + k2*32 + kb)
                                          : (dst_f + (long)em0c*64 + (k2-2)*32 + kb);
                tf[2*k2]   = ld4(q);
                tf[2*k2+1] = ld4(q + 4);
            }
        }
        if (c == 6) {            // pack seg2 tile0; load tile1 -> tf
            #pragma unroll
            for (int k2 = 0; k2 < 4; ++k2) s2f0[k2] = pack8(tf[2*k2], tf[2*k2+1]);
            #pragma unroll
            for (int k2 = 0; k2 < 4; ++k2) {
                const float* q = (k2 < 2) ? (ea    + (long)em1c*64 + k2*32 + kb)
                                          : (dst_f + (long)em1c*64 + (k2-2)*32 + kb);
                tf[2*k2]   = ld4(q);
                tf[2*k2+1] = ld4(q + 4);
            }
        }
        if (c == 8) {            // pack seg2 tile1; load temb tile0 -> tf
            #pragma unroll
            for (int k2 = 0; k2 < 4; ++k2) s2f1[k2] = pack8(tf[2*k2], tf[2*k2+1]);
            #pragma unroll
            for (int k2 = 0; k2 < 4; ++k2) {
                tf[2*k2]   = ld4(temb + (long)em0c * 128 + k2*32 + kb);
                tf[2*k2+1] = ld4(temb + (long)em0c * 128 + k2*32 + kb + 4);
            }
        }
        if (c == 10) {           // silu-pack temb tile0; load tile1 -> tf
            #pragma unroll
            for (int k2 = 0; k2 < 4; ++k2) {
                float4 va = tf[2*k2], vb = tf[2*k2+1];
                va.x=silu1(va.x); va.y=silu1(va.y); va.z=silu1(va.z); va.w=silu1(va.w);
                vb.x=silu1(vb.x); vb.y=silu1(vb.y); vb.z=silu1(vb.z); vb.w=silu1(vb.w);
                ttf0[k2] = pack8(va, vb);
            }
            #pragma unroll
            for (int k2 = 0; k2 < 4; ++k2) {
                tf[2*k2]   = ld4(temb + (long)em1c * 128 + k2*32 + kb);
                tf[2*k2+1] = ld4(temb + (long)em1c * 128 + k2*32 + kb + 4);
            }
        }
        {
            const int ks = c & 3;
            const bf16x8 a0 = (c < 4) ? s0f0[ks] : (c < 8) ? s1f0[ks] : s2f0[ks];
            const bf16x8 a1 = (c < 4) ? s0f1[ks] : (c < 8) ? s1f1[ks] : s2f1[ks];
            const short* wb = &Wb[c % 3][0];
            #pragma unroll
            for (int nt = 0; nt < 8; ++nt) {
                bf16x8 b = *reinterpret_cast<const bf16x8*>(&wb[nt*512 + l*8]);
                accX0[nt] = __builtin_amdgcn_mfma_f32_16x16x32_bf16(a0, b, accX0[nt], 0, 0, 0);
                accX1[nt] = __builtin_amdgcn_mfma_f32_16x16x32_bf16(a1, b, accX1[nt], 0, 0, 0);
            }
        }
    }

    // ---- bias + LayerNorm (LDS biases; chunks 12,13 in flight) ----
    #pragma unroll
    for (int nt = 0; nt < 8; ++nt) {
        float bv = sBias[(nt<<4) + ln];
        #pragma unroll
        for (int r = 0; r < 4; ++r) { accX0[nt][r] += bv; accX1[nt][r] += bv; }
    }
    #pragma unroll
    for (int r = 0; r < 4; ++r) {
        float p0 = 0.f, q0 = 0.f, p1 = 0.f, q1 = 0.f;
        #pragma unroll
        for (int nt = 0; nt < 8; ++nt) {
            float x0 = accX0[nt][r]; p0 += x0; q0 += x0*x0;
            float x1 = accX1[nt][r]; p1 += x1; q1 += x1*x1;
        }
        #pragma unroll
        for (int d2 = 1; d2 < 16; d2 <<= 1) {
            p0 += __shfl_xor(p0, d2); q0 += __shfl_xor(q0, d2);
            p1 += __shfl_xor(p1, d2); q1 += __shfl_xor(q1, d2);
        }
        float m0 = p0 * 0.0078125f, v0 = q0 * 0.0078125f - m0*m0;
        float m1 = p1 * 0.0078125f, v1 = q1 * 0.0078125f - m1*m1;
        float s0 = rsqrtf(v0 + 1e-6f), s1 = rsqrtf(v1 + 1e-6f);
        #pragma unroll
        for (int nt = 0; nt < 8; ++nt) {
            accX0[nt][r] = (accX0[nt][r] - m0) * s0;
            accX1[nt][r] = (accX1[nt][r] - m1) * s1;
        }
    }

    // ---- T stage: chunks 12..19, FiLM inline ----
    #pragma unroll
    for (int t = 0; t < 8; ++t) {
        if (t == 0) { WAITV(10); } else { WAITV(2); }
        BAR();
        STAGE8(14 + t);                          // chunks 14..21
        if (t == 0) {                            // silu-pack temb tile1 (loaded at c=10)
            #pragma unroll
            for (int k2 = 0; k2 < 4; ++k2) {
                float4 va = tf[2*k2], vb = tf[2*k2+1];
                va.x=silu1(va.x); va.y=silu1(va.y); va.z=silu1(va.z); va.w=silu1(va.w);
                vb.x=silu1(vb.x); vb.y=silu1(vb.y); vb.z=silu1(vb.z); vb.w=silu1(vb.w);
                ttf1[k2] = pack8(va, vb);
            }
        }
        {
            const short* wb = &Wb[(12 + t) % 3][0];
            #pragma unroll
            for (int jj = 0; jj < 2; ++jj) {
                f32x4 t0 = (f32x4){0.f,0.f,0.f,0.f};
                f32x4 t1 = (f32x4){0.f,0.f,0.f,0.f};
                #pragma unroll
                for (int ks = 0; ks < 4; ++ks) {
                    bf16x8 b = *reinterpret_cast<const bf16x8*>(&wb[(jj*4+ks)*512 + l*8]);
                    t0 = __builtin_amdgcn_mfma_f32_16x16x32_bf16(ttf0[ks], b, t0, 0, 0, 0);
                    t1 = __builtin_amdgcn_mfma_f32_16x16x32_bf16(ttf1[ks], b, t1, 0, 0, 0);
                }
                if (t < 4) {
                    const int jx = 2*t + jj;
                    float bsc = sBias[384 + (jx<<4) + ln];
                    #pragma unroll
                    for (int r = 0; r < 4; ++r) {
                        accX0[jx][r] *= (1.f + t0[r] + bsc);
                        accX1[jx][r] *= (1.f + t1[r] + bsc);
                    }
                } else {
                    const int jx = 2*(t-4) + jj;
                    float bsh = sBias[256 + (jx<<4) + ln];
                    #pragma unroll
                    for (int r = 0; r < 4; ++r) {
                        accX0[jx][r] += t0[r] + bsh;
                        accX1[jx][r] += t1[r] + bsh;
                    }
                }
            }
        }
    }

    // ---- transpose inv -> A-layout in idle Wb[1]; per-wave slice; 2 tiles seq ----
    short* tbW = &Wb[1][w * 1024];
    bf16x8 iaf0[4], iaf1[4];
    WAITL();
    BAR();                                       // all waves done with chunk 19 (buf 1)
    #pragma unroll
    for (int hp = 0; hp < 2; ++hp) {
        #pragma unroll
        for (int nt4 = 0; nt4 < 4; ++nt4) {
            const int nt = hp*4 + nt4;
            #pragma unroll
            for (int r = 0; r < 4; ++r)
                tbW[tswz((lg<<2) + r, (nt4<<4) + ln)] = f2bf(accX0[nt][r]);
        }
        #pragma unroll
        for (int k2 = 0; k2 < 2; ++k2)
            iaf0[hp*2 + k2] = *reinterpret_cast<const bf16x8*>(&tbW[tswz(ln, (k2<<5) + kb)]);
    }
    #pragma unroll
    for (int hp = 0; hp < 2; ++hp) {
        #pragma unroll
        for (int nt4 = 0; nt4 < 4; ++nt4) {
            const int nt = hp*4 + nt4;
            #pragma unroll
            for (int r = 0; r < 4; ++r)
                tbW[tswz((lg<<2) + r, (nt4<<4) + ln)] = f2bf(accX1[nt][r]);
        }
        #pragma unroll
        for (int k2 = 0; k2 < 2; ++k2)
            iaf1[hp*2 + k2] = *reinterpret_cast<const bf16x8*>(&tbW[tswz(ln, (k2<<5) + kb)]);
    }
    WAITL();                                     // transpose reads done before stage(22)

    // ---- W1 stage: chunks 20..23 ----
    f32x4 accY0[8], accY1[8];
    #pragma unroll
    for (int i = 0; i < 8; ++i) {
        accY0[i] = (f32x4){0.f,0.f,0.f,0.f};
        accY1[i] = (f32x4){0.f,0.f,0.f,0.f};
    }
    #pragma unroll
    for (int u = 0; u < 4; ++u) {
        if (u < 3) { WAITV(2); } else { WAITV(1); }
        BAR();
        if (u < 2)       { STAGE8(22 + u); }
        else if (u == 2) { STAGEW2(); }
        {
            const short* wb = &Wb[(20 + u) % 3][0];
            #pragma unroll
            for (int s = 0; s < 2; ++s) {
                const int nt = 2*u + s;
                #pragma unroll
                for (int ks = 0; ks < 4; ++ks) {
                    bf16x8 b = *reinterpret_cast<const bf16x8*>(&wb[(s*4+ks)*512 + l*8]);
                    accY0[nt] = __builtin_amdgcn_mfma_f32_16x16x32_bf16(iaf0[ks], b, accY0[nt], 0, 0, 0);
                    accY1[nt] = __builtin_amdgcn_mfma_f32_16x16x32_bf16(iaf1[ks], b, accY1[nt], 0, 0, 0);
                }
            }
        }
    }

    // ---- silu + transpose back in Wb[1] (chunk 22 consumed, never restaged) ----
    bf16x8 yaf0[4], yaf1[4];
    WAITL();
    BAR();
    #pragma unroll
    for (int hp = 0; hp < 2; ++hp) {
        #pragma unroll
        for (int nt4 = 0; nt4 < 4; ++nt4) {
            const int nt = hp*4 + nt4;
            float bv = sBias[128 + (nt<<4) + ln];
            #pragma unroll
            for (int r = 0; r < 4; ++r)
                tbW[tswz((lg<<2) + r, (nt4<<4) + ln)] = f2bf(silu1(accY0[nt][r] + bv));
        }
        #pragma unroll
        for (int k2 = 0; k2 < 2; ++k2)
            yaf0[hp*2 + k2] = *reinterpret_cast<const bf16x8*>(&tbW[tswz(ln, (k2<<5) + kb)]);
    }
    #pragma unroll
    for (int hp = 0; hp < 2; ++hp) {
        #pragma unroll
        for (int nt4 = 0; nt4 < 4; ++nt4) {
            const int nt = hp*4 + nt4;
            float bv = sBias[128 + (nt<<4) + ln];
            #pragma unroll
            for (int r = 0; r < 4; ++r)
                tbW[tswz((lg<<2) + r, (nt4<<4) + ln)] = f2bf(silu1(accY1[nt][r] + bv));
        }
        #pragma unroll
        for (int k2 = 0; k2 < 2; ++k2)
            yaf1[hp*2 + k2] = *reinterpret_cast<const bf16x8*>(&tbW[tswz(ln, (k2<<5) + kb)]);
    }

    // ---- W2 stage (chunk 24, buf 0) ----
    WAITV(0);
    BAR();
    f32x4 accZ0 = (f32x4){0.f,0.f,0.f,0.f};
    f32x4 accZ1 = (f32x4){0.f,0.f,0.f,0.f};
    {
        const short* wb = &Wb[0][0];
        #pragma unroll
        for (int ks = 0; ks < 4; ++ks) {
            bf16x8 b = *reinterpret_cast<const bf16x8*>(&wb[ks*512 + l*8]);
            accZ0 = __builtin_amdgcn_mfma_f32_16x16x32_bf16(yaf0[ks], b, accZ0, 0, 0, 0);
            accZ1 = __builtin_amdgcn_mfma_f32_16x16x32_bf16(yaf1[ks], b, accZ1, 0, 0, 0);
        }
    }

    // ---- epilogue: geometry loads + math + tanh + head-mean + atomic scatter ----
    {
        const float csc = cscale[0];
        // tile 0
        {
            float dx = pos[ir0*3+0] - pos[ic0*3+0];
            float dy = pos[ir0*3+1] - pos[ic0*3+1];
            float dz = pos[ir0*3+2] - pos[ic0*3+2];
            float a0v = adj[em0c*3+0], a1v = adj[em0c*3+1], a2v = adj[em0c*3+2];
            float nrm = sqrtf(dx*dx + dy*dy + dz*dz);
            float sc  = csc / fmaxf(nrm, 1e-8f);
            float cdx = dx * sc, cdy = dy * sc, cdz = dz * sc;
            #pragma unroll
            for (int r = 0; r < 4; ++r) {
                const int m = (lg<<2) + r;
                float z  = tanh1(accZ0[r]);
                float w0 = __shfl(a0v, m), w1 = __shfl(a1v, m), w2 = __shfl(a2v, m);
                int   irm  = __shfl(ir0, m);
                float cdxm = __shfl(cdx, m), cdym = __shfl(cdy, m), cdzm = __shfl(cdz, m);
                float wt = (ln == 0) ? 1.0f : (ln == 1 ? w0 : (ln == 2 ? w1 : (ln == 3 ? w2 : 0.0f)));
                float v = z * wt;
                v += __shfl_xor(v, 1);
                v += __shfl_xor(v, 2);
                float s = v * 0.25f;
                if (ln < 3 && (e0w + m) < E_EDGES) {
                    float cdc = (ln == 0) ? cdxm : (ln == 1 ? cdym : cdzm);
                    atomicAdd(&out[(long)irm*3 + ln], cdc * s);
                }
            }
        }
        // tile 1
        {
            float dx = pos[ir1*3+0] - pos[ic1*3+0];
            float dy = pos[ir1*3+1] - pos[ic1*3+1];
            float dz = pos[ir1*3+2] - pos[ic1*3+2];
            float a0v = adj[em1c*3+0], a1v = adj[em1c*3+1], a2v = adj[em1c*3+2];
            float nrm = sqrtf(dx*dx + dy*dy + dz*dz);
            float sc  = csc / fmaxf(nrm, 1e-8f);
            float cdx = dx * sc, cdy = dy * sc, cdz = dz * sc;
            #pragma unroll
            for (int r = 0; r < 4; ++r) {
                const int m = (lg<<2) + r;
                float z  = tanh1(accZ1[r]);
                float w0 = __shfl(a0v, m), w1 = __shfl(a1v, m), w2 = __shfl(a2v, m);
                int   irm  = __shfl(ir1, m);
                float cdxm = __shfl(cdx, m), cdym = __shfl(cdy, m), cdzm = __shfl(cdz, m);
                float wt = (ln == 0) ? 1.0f : (ln == 1 ? w0 : (ln == 2 ? w1 : (ln == 3 ? w2 : 0.0f)));
                float v = z * wt;
                v += __shfl_xor(v, 1);
                v += __shfl_xor(v, 2);
                float s = v * 0.25f;
                if (ln < 3 && (e0w + 16 + m) < E_EDGES) {
                    float cdc = (ln == 0) ? cdxm : (ln == 1 ? cdym : cdzm);
                    atomicAdd(&out[(long)irm*3 + ln], cdc * s);
                }
            }
        }
    }
    #undef STAGE8
    #undef STAGEW2
}

extern "C" void kernel_launch(void* const* d_in, const int* in_sizes, int n_in,
                              void* d_out, int out_size, void* d_ws, size_t ws_size,
                              hipStream_t stream) {
    const float* h     = (const float*)d_in[0];
    const float* pos   = (const float*)d_in[1];
    const float* ea    = (const float*)d_in[2];
    const float* dist  = (const float*)d_in[3];
    const float* temb  = (const float*)d_in[4];
    const float* adj   = (const float*)d_in[5];
    const float* Wt    = (const float*)d_in[6];
    const float* bt    = (const float*)d_in[7];
    const float* Win   = (const float*)d_in[8];
    const float* bin   = (const float*)d_in[9];
    const float* W1    = (const float*)d_in[10];
    const float* b1    = (const float*)d_in[11];
    const float* W2    = (const float*)d_in[12];
    const float* cs    = (const float*)d_in[13];
    const int*   ei    = (const int*)d_in[14];
    float*       out   = (float*)d_out;
    short*       ws    = (short*)d_ws;

    const size_t W_SHORTS  = 25 * 4096;                       // 102400
    const size_t H_SHORTS  = (size_t)N_NODES * 128;           // 12.8M
    const bool   use_hbf   = ws_size >= (W_SHORTS + H_SHORTS) * sizeof(short);
    short*       hbf       = ws + W_SHORTS;

    pack_weights_kernel<<<(196*512 + 255) / 256, 256, 0, stream>>>(Wt, Win, W1, W2, ws);
    if (use_hbf)
        h_pack_kernel<<<(int)(H_SHORTS / 8 / 256), 256, 0, stream>>>(h, hbf);
    hipMemcpyAsync(out, pos, (size_t)out_size * sizeof(float),
                   hipMemcpyDeviceToDevice, stream);
    const int grid = (E_EDGES + 127) / 128;
    if (use_hbf)
        edge_kernel<true><<<grid, 256, 0, stream>>>(h, hbf, pos, ea, dist, temb, adj,
                                                    bt, bin, b1, cs, ei, ws, out);
    else
        edge_kernel<false><<<grid, 256, 0, stream>>>(h, hbf, pos, ea, dist, temb, adj,
                                                     bt, bin, b1, cs, ei, ws, out);
}

// Round 13
// 582.143 us; speedup vs baseline: 1.4835x; 1.2306x over previous
//
#include <hip/hip_runtime.h>
#include <hip/hip_bf16.h>

#define E_EDGES 1000000

typedef __attribute__((ext_vector_type(8))) short bf16x8;
typedef __attribute__((ext_vector_type(4))) float f32x4;

#define WAITV(N) asm volatile("s_waitcnt vmcnt(" #N ")" ::: "memory")
#define WAITL()  asm volatile("s_waitcnt lgkmcnt(0)" ::: "memory")
#define BAR()    __builtin_amdgcn_s_barrier()

__device__ __forceinline__ short f2bf(float f) {
    union { __bf16 b; short s; } u;
    u.b = (__bf16)f;
    return u.s;
}
__device__ __forceinline__ bf16x8 pack8(float4 a, float4 b) {
    bf16x8 r;
    r[0]=f2bf(a.x); r[1]=f2bf(a.y); r[2]=f2bf(a.z); r[3]=f2bf(a.w);
    r[4]=f2bf(b.x); r[5]=f2bf(b.y); r[6]=f2bf(b.z); r[7]=f2bf(b.w);
    return r;
}
__device__ __forceinline__ float4 ld4(const float* p) {
    return *reinterpret_cast<const float4*>(p);
}
__device__ __forceinline__ float silu1(float x) { return x / (1.f + __expf(-x)); }
__device__ __forceinline__ float tanh1(float x) {
    float e = __expf(2.f * x);
    return 1.f - 2.f / (e + 1.f);
}

// ---------------- weight pre-pack: f32 -> bf16 frags in CHUNK-LINEAR order ------
__global__ void pack_weights_kernel(const float* __restrict__ Wt,
                                    const float* __restrict__ Win,
                                    const float* __restrict__ W1,
                                    const float* __restrict__ W2,
                                    short* __restrict__ ws)
{
    int gid = blockIdx.x * 256 + threadIdx.x;
    if (gid >= 196 * 512) return;
    int frag = gid >> 9, within = gid & 511;
    int l = within >> 3, j = within & 7;
    int lg = l >> 4, ln = l & 15;
    int krow = (lg << 3) + j;
    float v;
    if (frag < 96) {
        int cs = frag >> 3, nt = frag & 7;
        int seg = cs >> 2, ks = cs & 3;
        int k = seg * 128 + ks * 32 + krow;
        v = Win[k * 128 + nt * 16 + ln];
    } else if (frag < 160) {
        int t = frag - 96, ch = t >> 3, sub = t & 7;
        int jj = sub >> 2, ks = sub & 3;
        int jcol = (ch < 4) ? (8 + 2 * ch + jj) : (2 * (ch - 4) + jj);
        int k = ks * 32 + krow;
        v = Wt[k * 256 + jcol * 16 + ln];
    } else if (frag < 192) {
        int t = frag - 160, ch = t >> 3, sub = t & 7;
        int nt = 2 * ch + (sub >> 2), ks = sub & 3;
        int k = ks * 32 + krow;
        v = W1[k * 128 + nt * 16 + ln];
    } else {
        int ks = frag - 192;
        int k = ks * 32 + krow;
        v = (ln < 4) ? W2[k * 4 + ln] : 0.0f;
    }
    ws[gid] = f2bf(v);
}

__device__ __forceinline__ void stage_frag(const short* gsrc, short* ldst) {
    __builtin_amdgcn_global_load_lds(
        (const __attribute__((address_space(1))) void*)gsrc,
        (__attribute__((address_space(3))) void*)ldst, 16, 0, 0);
}

// swizzled transpose index (shorts) within a per-wave 16x64 slice
__device__ __forceinline__ int tswz(int row, int colS) {
    return (row * 64 + colS) ^ ((row & 7) << 3);
}

// ------ fused edge kernel: 4 waves x 16 edges; depth-3 shared chunk rotation;
//        transposes reuse idle Wb[1] slice -> LDS 24576 B -> 6 blocks/CU ------
__global__ __launch_bounds__(256, 3)
void edge_kernel(const float* __restrict__ h,
                 const float* __restrict__ pos,
                 const float* __restrict__ ea,
                 const float* __restrict__ dst_f,
                 const float* __restrict__ temb,
                 const float* __restrict__ adj,
                 const float* __restrict__ btime,
                 const float* __restrict__ bin,
                 const float* __restrict__ b1,
                 const float* __restrict__ cscale,
                 const int*   __restrict__ ei,
                 const short* __restrict__ ws,
                 float* __restrict__ out)
{
    __shared__ __align__(16) short Wb[3][4096];   // 3 x 8 KB rotating weight chunks (24 KB)

    const int tid = threadIdx.x;
    const int w   = tid >> 6;
    const int l   = tid & 63;
    const int ln  = l & 15;
    const int lg  = l >> 4;
    const int kb  = lg << 3;
    const int e0w = blockIdx.x * 64 + w * 16;
    const int em  = e0w + ln;                // this lane's edge (1 tile/wave)

    const int ir = ei[em];
    const int ic = ei[E_EDGES + em];

    // geometry raw loads (math deferred to epilogue)
    const float px0 = pos[ir*3+0], py0 = pos[ir*3+1], pz0 = pos[ir*3+2];
    const float px1 = pos[ic*3+0], py1 = pos[ic*3+1], pz1 = pos[ic*3+2];
    const float a0  = adj[em*3+0], a1  = adj[em*3+1], a2  = adj[em*3+2];
    const float csc = cscale[0];

    // bias preloads -> registers (no VMEM in later phases)
    float btsh[8], btsc[8], binr[8], b1r[8];
    #pragma unroll
    for (int j = 0; j < 8; ++j) {
        btsh[j] = btime[(j<<4) + ln];
        btsc[j] = btime[128 + (j<<4) + ln];
        binr[j] = bin[(j<<4) + ln];
        b1r[j]  = b1[(j<<4) + ln];
    }

    #define STAGE8(p) { \
        const short* g_ = ws + (p) * 4096 + (w*2) * 512 + l * 8; \
        short* d_ = &Wb[(p) % 3][(w*2) * 512]; \
        stage_frag(g_, d_); \
        stage_frag(g_ + 512, d_ + 512); }
    #define STAGEW2() { \
        stage_frag(ws + 24 * 4096 + w * 512 + l * 8, &Wb[0][w * 512]); }

    // ---- prologue: seg0 A loads, then chunks 0 and 1 ----
    float4 Abuf[8];
    #pragma unroll
    for (int k2 = 0; k2 < 4; ++k2) {
        Abuf[2*k2]   = ld4(h + (long)ir * 128 + k2*32 + kb);
        Abuf[2*k2+1] = ld4(h + (long)ir * 128 + k2*32 + kb + 4);
    }
    STAGE8(0);
    STAGE8(1);

    f32x4 accX[8];
    #pragma unroll
    for (int i = 0; i < 8; ++i) accX[i] = (f32x4){0.f,0.f,0.f,0.f};
    bf16x8 af[4];

    // ---- X = h_input @ W_in : chunks 0..11 ----
    #pragma unroll
    for (int c = 0; c < 12; ++c) {
        // ledger: stage(c+1) newest (2 ops); 8-load A batches at c in {1,5,9}
        if (c == 2 || c == 3 || c == 6 || c == 7 || c == 10 || c == 11) { WAITV(10); }
        else { WAITV(2); }
        BAR();                                   // chunk c visible; buf (c+2)%3 free
        STAGE8(c + 2);                           // chunks 2..13
        if (c == 1) {            // seg1: h[col]
            #pragma unroll
            for (int k2 = 0; k2 < 4; ++k2) {
                Abuf[2*k2]   = ld4(h + (long)ic * 128 + k2*32 + kb);
                Abuf[2*k2+1] = ld4(h + (long)ic * 128 + k2*32 + kb + 4);
            }
        }
        if (c == 5) {            // seg2: ea | dist
            #pragma unroll
            for (int k2 = 0; k2 < 4; ++k2) {
                const float* q = (k2 < 2) ? (ea    + (long)em*64 + k2*32 + kb)
                                          : (dst_f + (long)em*64 + (k2-2)*32 + kb);
                Abuf[2*k2]   = ld4(q);
                Abuf[2*k2+1] = ld4(q + 4);
            }
        }
        if (c == 9) {            // temb rows for T stage
            #pragma unroll
            for (int k2 = 0; k2 < 4; ++k2) {
                Abuf[2*k2]   = ld4(temb + (long)em * 128 + k2*32 + kb);
                Abuf[2*k2+1] = ld4(temb + (long)em * 128 + k2*32 + kb + 4);
            }
        }
        if (c == 0 || c == 4 || c == 8) {        // pack this seg's A fragments
            #pragma unroll
            for (int k2 = 0; k2 < 4; ++k2) af[k2] = pack8(Abuf[2*k2], Abuf[2*k2+1]);
        }
        {
            const int ks = c & 3;
            const short* wb = &Wb[c % 3][0];
            #pragma unroll
            for (int nt = 0; nt < 8; ++nt) {
                bf16x8 b = *reinterpret_cast<const bf16x8*>(&wb[nt*512 + l*8]);
                accX[nt] = __builtin_amdgcn_mfma_f32_16x16x32_bf16(af[ks], b, accX[nt], 0, 0, 0);
            }
        }
    }

    // ---- bias + LayerNorm (register-only; chunks 12,13 in flight) ----
    #pragma unroll
    for (int nt = 0; nt < 8; ++nt) {
        #pragma unroll
        for (int r = 0; r < 4; ++r) accX[nt][r] += binr[nt];
    }
    #pragma unroll
    for (int r = 0; r < 4; ++r) {
        float p = 0.f, q = 0.f;
        #pragma unroll
        for (int nt = 0; nt < 8; ++nt) { float x = accX[nt][r]; p += x; q += x*x; }
        #pragma unroll
        for (int d2 = 1; d2 < 16; d2 <<= 1) { p += __shfl_xor(p, d2); q += __shfl_xor(q, d2); }
        float mean = p * 0.0078125f;
        float var  = q * 0.0078125f - mean * mean;
        float rstd = rsqrtf(var + 1e-6f);
        #pragma unroll
        for (int nt = 0; nt < 8; ++nt)
            accX[nt][r] = (accX[nt][r] - mean) * rstd;
    }

    // ---- silu(temb) fragments from Abuf ----
    bf16x8 ttf[4];
    #pragma unroll
    for (int k2 = 0; k2 < 4; ++k2) {
        float4 va = Abuf[2*k2], vb = Abuf[2*k2+1];
        va.x=silu1(va.x); va.y=silu1(va.y); va.z=silu1(va.z); va.w=silu1(va.w);
        vb.x=silu1(vb.x); vb.y=silu1(vb.y); vb.z=silu1(vb.z); vb.w=silu1(vb.w);
        ttf[k2] = pack8(va, vb);
    }

    // ---- T stage: chunks 12..19, FiLM inline ----
    #pragma unroll
    for (int t = 0; t < 8; ++t) {
        WAITV(2);
        BAR();
        STAGE8(14 + t);                          // chunks 14..21
        {
            const short* wb = &Wb[(12 + t) % 3][0];
            #pragma unroll
            for (int jj = 0; jj < 2; ++jj) {
                f32x4 tt = (f32x4){0.f,0.f,0.f,0.f};
                #pragma unroll
                for (int ks = 0; ks < 4; ++ks) {
                    bf16x8 b = *reinterpret_cast<const bf16x8*>(&wb[(jj*4+ks)*512 + l*8]);
                    tt = __builtin_amdgcn_mfma_f32_16x16x32_bf16(ttf[ks], b, tt, 0, 0, 0);
                }
                if (t < 4) {
                    const int jx = 2*t + jj;
                    #pragma unroll
                    for (int r = 0; r < 4; ++r) accX[jx][r] *= (1.f + tt[r] + btsc[jx]);
                } else {
                    const int jx = 2*(t-4) + jj;
                    #pragma unroll
                    for (int r = 0; r < 4; ++r) accX[jx][r] += tt[r] + btsh[jx];
                }
            }
        }
    }

    // ---- transpose inv -> A-layout, reusing idle Wb[1] (chunk 19 consumed,
    //      not restaged until chunk 22). lgkmcnt(0)+BAR guards the reuse. ----
    short* tbW = &Wb[1][w * 1024];
    bf16x8 iaf[4];
    WAITL();                                     // own buf-1 ds_reads (t=7) retired
    BAR();                                       // all waves done with chunk 19
    #pragma unroll
    for (int hp = 0; hp < 2; ++hp) {
        #pragma unroll
        for (int nt4 = 0; nt4 < 4; ++nt4) {
            const int nt = hp*4 + nt4;
            #pragma unroll
            for (int r = 0; r < 4; ++r)
                tbW[tswz((lg<<2) + r, (nt4<<4) + ln)] = f2bf(accX[nt][r]);
        }
        #pragma unroll
        for (int k2 = 0; k2 < 2; ++k2)
            iaf[hp*2 + k2] = *reinterpret_cast<const bf16x8*>(&tbW[tswz(ln, (k2<<5) + kb)]);
    }
    WAITL();                                     // transpose reads done before stage(22)

    // ---- W1 stage: chunks 20..23 ----
    f32x4 accY[8];
    #pragma unroll
    for (int i = 0; i < 8; ++i) accY[i] = (f32x4){0.f,0.f,0.f,0.f};
    #pragma unroll
    for (int u = 0; u < 4; ++u) {
        if (u < 3) { WAITV(2); } else { WAITV(1); }
        BAR();
        if (u < 2)       { STAGE8(22 + u); }     // chunks 22, 23
        else if (u == 2) { STAGEW2(); }          // chunk 24 (1 op/wave)
        {
            const short* wb = &Wb[(20 + u) % 3][0];
            #pragma unroll
            for (int s = 0; s < 2; ++s) {
                const int nt = 2*u + s;
                #pragma unroll
                for (int ks = 0; ks < 4; ++ks) {
                    bf16x8 b = *reinterpret_cast<const bf16x8*>(&wb[(s*4+ks)*512 + l*8]);
                    accY[nt] = __builtin_amdgcn_mfma_f32_16x16x32_bf16(iaf[ks], b, accY[nt], 0, 0, 0);
                }
            }
        }
    }

    // ---- silu + transpose back, reusing Wb[1] again (chunk 22 consumed,
    //      never restaged) ----
    bf16x8 yaf[4];
    WAITL();
    BAR();
    #pragma unroll
    for (int hp = 0; hp < 2; ++hp) {
        #pragma unroll
        for (int nt4 = 0; nt4 < 4; ++nt4) {
            const int nt = hp*4 + nt4;
            #pragma unroll
            for (int r = 0; r < 4; ++r)
                tbW[tswz((lg<<2) + r, (nt4<<4) + ln)] = f2bf(silu1(accY[nt][r] + b1r[nt]));
        }
        #pragma unroll
        for (int k2 = 0; k2 < 2; ++k2)
            yaf[hp*2 + k2] = *reinterpret_cast<const bf16x8*>(&tbW[tswz(ln, (k2<<5) + kb)]);
    }

    // ---- W2 stage (chunk 24, buf 0) ----
    WAITV(0);
    BAR();
    f32x4 accZ = (f32x4){0.f,0.f,0.f,0.f};
    {
        const short* wb = &Wb[0][0];
        #pragma unroll
        for (int ks = 0; ks < 4; ++ks) {
            bf16x8 b = *reinterpret_cast<const bf16x8*>(&wb[ks*512 + l*8]);
            accZ = __builtin_amdgcn_mfma_f32_16x16x32_bf16(yaf[ks], b, accZ, 0, 0, 0);
        }
    }

    // ---- epilogue: geometry math + tanh + head-mean + atomic scatter ----
    {
        float dx = px0 - px1, dy = py0 - py1, dz = pz0 - pz1;
        float nrm = sqrtf(dx*dx + dy*dy + dz*dz);
        float sc  = csc / fmaxf(nrm, 1e-8f);
        float cdx = dx * sc, cdy = dy * sc, cdz = dz * sc;
        #pragma unroll
        for (int r = 0; r < 4; ++r) {
            const int m = (lg<<2) + r;           // edge within the wave tile
            float z  = tanh1(accZ[r]);
            float w0 = __shfl(a0, m), w1 = __shfl(a1, m), w2 = __shfl(a2, m);
            int   irm  = __shfl(ir, m);
            float cdxm = __shfl(cdx, m), cdym = __shfl(cdy, m), cdzm = __shfl(cdz, m);
            float wt = (ln == 0) ? 1.0f : (ln == 1 ? w0 : (ln == 2 ? w1 : (ln == 3 ? w2 : 0.0f)));
            float v = z * wt;
            v += __shfl_xor(v, 1);
            v += __shfl_xor(v, 2);               // heads 0..3 summed within 4-lane group
            float s = v * 0.25f;
            if (ln < 3) {
                float cdc = (ln == 0) ? cdxm : (ln == 1 ? cdym : cdzm);
                atomicAdd(&out[(long)irm*3 + ln], cdc * s);
            }
        }
    }
    #undef STAGE8
    #undef STAGEW2
}

extern "C" void kernel_launch(void* const* d_in, const int* in_sizes, int n_in,
                              void* d_out, int out_size, void* d_ws, size_t ws_size,
                              hipStream_t stream) {
    const float* h     = (const float*)d_in[0];
    const float* pos   = (const float*)d_in[1];
    const float* ea    = (const float*)d_in[2];
    const float* dist  = (const float*)d_in[3];
    const float* temb  = (const float*)d_in[4];
    const float* adj   = (const float*)d_in[5];
    const float* Wt    = (const float*)d_in[6];
    const float* bt    = (const float*)d_in[7];
    const float* Win   = (const float*)d_in[8];
    const float* bin   = (const float*)d_in[9];
    const float* W1    = (const float*)d_in[10];
    const float* b1    = (const float*)d_in[11];
    const float* W2    = (const float*)d_in[12];
    const float* cs    = (const float*)d_in[13];
    const int*   ei    = (const int*)d_in[14];
    float*       out   = (float*)d_out;
    short*       ws    = (short*)d_ws;

    pack_weights_kernel<<<(196*512 + 255) / 256, 256, 0, stream>>>(Wt, Win, W1, W2, ws);
    hipMemcpyAsync(out, pos, (size_t)out_size * sizeof(float),
                   hipMemcpyDeviceToDevice, stream);
    edge_kernel<<<E_EDGES / 64, 256, 0, stream>>>(h, pos, ea, dist, temb, adj,
                                                  bt, bin, b1, cs, ei, ws, out);
}

// Round 14
// 552.841 us; speedup vs baseline: 1.5622x; 1.0530x over previous
//
#include <hip/hip_runtime.h>
#include <hip/hip_bf16.h>

#define E_EDGES 1000000
#define N_NODES 100000

typedef __attribute__((ext_vector_type(8))) short bf16x8;
typedef __attribute__((ext_vector_type(4))) float f32x4;

#define WAITV(N) asm volatile("s_waitcnt vmcnt(" #N ")" ::: "memory")
#define WAITL()  asm volatile("s_waitcnt lgkmcnt(0)" ::: "memory")
#define BAR()    __builtin_amdgcn_s_barrier()

__device__ __forceinline__ short f2bf(float f) {
    union { __bf16 b; short s; } u;
    u.b = (__bf16)f;
    return u.s;
}
__device__ __forceinline__ bf16x8 pack8(float4 a, float4 b) {
    bf16x8 r;
    r[0]=f2bf(a.x); r[1]=f2bf(a.y); r[2]=f2bf(a.z); r[3]=f2bf(a.w);
    r[4]=f2bf(b.x); r[5]=f2bf(b.y); r[6]=f2bf(b.z); r[7]=f2bf(b.w);
    return r;
}
__device__ __forceinline__ float4 ld4(const float* p) {
    return *reinterpret_cast<const float4*>(p);
}
__device__ __forceinline__ float silu1(float x) { return x / (1.f + __expf(-x)); }
__device__ __forceinline__ float tanh1(float x) {
    float e = __expf(2.f * x);
    return 1.f - 2.f / (e + 1.f);
}

// ---------------- weight pre-pack: f32 -> bf16 frags in CHUNK-LINEAR order ------
// W_in chunk order REORDERED for the edge kernel's consumption:
//   X chunks 0-3: W_in rows 256..383 (ea|dist), 4-7: rows 0..127 (h_row),
//   8-11: rows 128..255 (h_col).
__global__ void pack_weights_kernel(const float* __restrict__ Wt,
                                    const float* __restrict__ Win,
                                    const float* __restrict__ W1,
                                    const float* __restrict__ W2,
                                    short* __restrict__ ws)
{
    int gid = blockIdx.x * 256 + threadIdx.x;
    if (gid >= 196 * 512) return;
    int frag = gid >> 9, within = gid & 511;
    int l = within >> 3, j = within & 7;
    int lg = l >> 4, ln = l & 15;
    int krow = (lg << 3) + j;
    float v;
    if (frag < 96) {
        int cs = frag >> 3, nt = frag & 7;
        int seg = cs >> 2, ks = cs & 3;
        int base = (seg == 0) ? 256 : (seg == 1) ? 0 : 128;   // ea|dist, h_row, h_col
        int k = base + ks * 32 + krow;
        v = Win[k * 128 + nt * 16 + ln];
    } else if (frag < 160) {
        int t = frag - 96, ch = t >> 3, sub = t & 7;
        int jj = sub >> 2, ks = sub & 3;
        int jcol = (ch < 4) ? (8 + 2 * ch + jj) : (2 * (ch - 4) + jj);
        int k = ks * 32 + krow;
        v = Wt[k * 256 + jcol * 16 + ln];
    } else if (frag < 192) {
        int t = frag - 160, ch = t >> 3, sub = t & 7;
        int nt = 2 * ch + (sub >> 2), ks = sub & 3;
        int k = ks * 32 + krow;
        v = W1[k * 128 + nt * 16 + ln];
    } else {
        int ks = frag - 192;
        int k = ks * 32 + krow;
        v = (ln < 4) ? W2[k * 4 + ln] : 0.0f;
    }
    ws[gid] = f2bf(v);
}

// ---------------- h -> bf16 table (one streaming pass) -------------------------
__global__ void h_pack_kernel(const float* __restrict__ h, short* __restrict__ hbf) {
    long i = (long)(blockIdx.x * 256 + threadIdx.x) * 8;
    if (i >= (long)N_NODES * 128) return;
    float4 a = ld4(h + i), b = ld4(h + i + 4);
    *reinterpret_cast<bf16x8*>(hbf + i) = pack8(a, b);
}

__device__ __forceinline__ void stage_frag(const short* gsrc, short* ldst) {
    __builtin_amdgcn_global_load_lds(
        (const __attribute__((address_space(1))) void*)gsrc,
        (__attribute__((address_space(3))) void*)ldst, 16, 0, 0);
}

// swizzled transpose index (shorts) within a per-wave 16x64 slice
__device__ __forceinline__ int tswz(int row, int colS) {
    return (row * 64 + colS) ^ ((row & 7) << 3);
}

// ------ fused edge kernel: 4 waves x 16 edges; depth-3 shared chunk rotation;
//        transposes in idle Wb[1]; VGPR diet: sBias LDS, bf16 h-table, deferred
//        geometry. Schedule identical to R13. ------
template<bool HBF>
__global__ __launch_bounds__(256, 3)
void edge_kernel(const float* __restrict__ h,
                 const short* __restrict__ hbf,
                 const float* __restrict__ pos,
                 const float* __restrict__ ea,
                 const float* __restrict__ dst_f,
                 const float* __restrict__ temb,
                 const float* __restrict__ adj,
                 const float* __restrict__ btime,
                 const float* __restrict__ bin,
                 const float* __restrict__ b1,
                 const float* __restrict__ cscale,
                 const int*   __restrict__ ei,
                 const short* __restrict__ ws,
                 float* __restrict__ out)
{
    __shared__ __align__(16) short Wb[3][4096];   // 3 x 8 KB rotating weight chunks
    __shared__ float sBias[512];                  // [0:128) bin, [128:256) b1,
                                                  // [256:384) bt_shift, [384:512) bt_scale

    const int tid = threadIdx.x;
    const int w   = tid >> 6;
    const int l   = tid & 63;
    const int ln  = l & 15;
    const int lg  = l >> 4;
    const int kb  = lg << 3;
    const int e0w = blockIdx.x * 64 + w * 16;
    const int em  = e0w + ln;                // this lane's edge (1 tile/wave)

    const int ir = ei[em];
    const int ic = ei[E_EDGES + em];

    // biases -> LDS FIRST (their global loads drain before any stage op issues)
    #pragma unroll
    for (int i = 0; i < 2; ++i) {
        int idx = tid + i * 256;
        float v = (idx < 128) ? bin[idx] : (idx < 256) ? b1[idx - 128] : btime[idx - 256];
        sBias[idx] = v;
    }
    WAITL();

    #define STAGE8(p) { \
        const short* g_ = ws + (p) * 4096 + (w*2) * 512 + l * 8; \
        short* d_ = &Wb[(p) % 3][(w*2) * 512]; \
        stage_frag(g_, d_); \
        stage_frag(g_ + 512, d_ + 512); }
    #define STAGEW2() { \
        stage_frag(ws + 24 * 4096 + w * 512 + l * 8, &Wb[0][w * 512]); }

    // ---- prologue: ea|dist f32 loads, h_row frags, chunks 0,1 ----
    float4 tf[8];                            // time-shared f32 staging (ea|dist, later temb)
    #pragma unroll
    for (int k2 = 0; k2 < 4; ++k2) {
        const float* q = (k2 < 2) ? (ea    + (long)em*64 + k2*32 + kb)
                                  : (dst_f + (long)em*64 + (k2-2)*32 + kb);
        tf[2*k2]   = ld4(q);
        tf[2*k2+1] = ld4(q + 4);
    }
    bf16x8 af_b[4];                          // h_row fragments
    if (HBF) {
        #pragma unroll
        for (int k2 = 0; k2 < 4; ++k2)
            af_b[k2] = *reinterpret_cast<const bf16x8*>(hbf + (long)ir * 128 + k2*32 + kb);
    } else {
        #pragma unroll
        for (int k2 = 0; k2 < 4; ++k2)
            af_b[k2] = pack8(ld4(h + (long)ir*128 + k2*32 + kb),
                             ld4(h + (long)ir*128 + k2*32 + kb + 4));
    }
    STAGE8(0);
    STAGE8(1);
    if (HBF) { WAITV(8); } else { WAITV(4); }   // ea|dist done (fallback packs h eagerly)
    bf16x8 af_a[4];                          // ea|dist fragments
    #pragma unroll
    for (int k2 = 0; k2 < 4; ++k2) af_a[k2] = pack8(tf[2*k2], tf[2*k2+1]);

    f32x4 accX[8];
    #pragma unroll
    for (int i = 0; i < 8; ++i) accX[i] = (f32x4){0.f,0.f,0.f,0.f};
    bf16x8 af_c[4];                          // h_col fragments (loaded at c==3)

    // ---- X = h_input @ W_in : chunks 0..11 (ea|dist, h_row, h_col) ----
    #pragma unroll
    for (int c = 0; c < 12; ++c) {
        if (HBF) {
            if (c == 4 || c == 5) { WAITV(6); } else { WAITV(2); }
        } else {
            if (c == 4 || c == 5) { WAITV(10); } else { WAITV(2); }
        }
        BAR();                               // chunk c visible; buf (c+2)%3 free
        if (c == 11) {                       // temb f32 loads (consumed post-loop)
            #pragma unroll
            for (int k2 = 0; k2 < 4; ++k2) {
                tf[2*k2]   = ld4(temb + (long)em * 128 + k2*32 + kb);
                tf[2*k2+1] = ld4(temb + (long)em * 128 + k2*32 + kb + 4);
            }
        }
        STAGE8(c + 2);                       // chunks 2..13
        if (c == 3) {                        // h_col fragment loads
            if (HBF) {
                #pragma unroll
                for (int k2 = 0; k2 < 4; ++k2)
                    af_c[k2] = *reinterpret_cast<const bf16x8*>(hbf + (long)ic * 128 + k2*32 + kb);
            } else {
                #pragma unroll
                for (int k2 = 0; k2 < 4; ++k2)
                    af_c[k2] = pack8(ld4(h + (long)ic*128 + k2*32 + kb),
                                     ld4(h + (long)ic*128 + k2*32 + kb + 4));
            }
        }
        {
            const int ks = c & 3;
            const bf16x8 a_use = (c < 4) ? af_a[ks] : (c < 8) ? af_b[ks] : af_c[ks];
            const short* wb = &Wb[c % 3][0];
            #pragma unroll
            for (int nt = 0; nt < 8; ++nt) {
                bf16x8 b = *reinterpret_cast<const bf16x8*>(&wb[nt*512 + l*8]);
                accX[nt] = __builtin_amdgcn_mfma_f32_16x16x32_bf16(a_use, b, accX[nt], 0, 0, 0);
            }
        }
    }

    // ---- bias + LayerNorm (sBias; chunks 12,13 + temb in flight) ----
    #pragma unroll
    for (int nt = 0; nt < 8; ++nt) {
        float bv = sBias[(nt<<4) + ln];
        #pragma unroll
        for (int r = 0; r < 4; ++r) accX[nt][r] += bv;
    }
    #pragma unroll
    for (int r = 0; r < 4; ++r) {
        float p = 0.f, q = 0.f;
        #pragma unroll
        for (int nt = 0; nt < 8; ++nt) { float x = accX[nt][r]; p += x; q += x*x; }
        #pragma unroll
        for (int d2 = 1; d2 < 16; d2 <<= 1) { p += __shfl_xor(p, d2); q += __shfl_xor(q, d2); }
        float mean = p * 0.0078125f;
        float var  = q * 0.0078125f - mean * mean;
        float rstd = rsqrtf(var + 1e-6f);
        #pragma unroll
        for (int nt = 0; nt < 8; ++nt)
            accX[nt][r] = (accX[nt][r] - mean) * rstd;
    }

    // ---- silu(temb) fragments (drain temb, keep stage(13) in flight) ----
    WAITV(2);
    bf16x8 ttf[4];
    #pragma unroll
    for (int k2 = 0; k2 < 4; ++k2) {
        float4 va = tf[2*k2], vb = tf[2*k2+1];
        va.x=silu1(va.x); va.y=silu1(va.y); va.z=silu1(va.z); va.w=silu1(va.w);
        vb.x=silu1(vb.x); vb.y=silu1(vb.y); vb.z=silu1(vb.z); vb.w=silu1(vb.w);
        ttf[k2] = pack8(va, vb);
    }

    // ---- T stage: chunks 12..19, FiLM inline (sBias) ----
    #pragma unroll
    for (int t = 0; t < 8; ++t) {
        WAITV(2);
        BAR();
        STAGE8(14 + t);                      // chunks 14..21
        {
            const short* wb = &Wb[(12 + t) % 3][0];
            #pragma unroll
            for (int jj = 0; jj < 2; ++jj) {
                f32x4 tt = (f32x4){0.f,0.f,0.f,0.f};
                #pragma unroll
                for (int ks = 0; ks < 4; ++ks) {
                    bf16x8 b = *reinterpret_cast<const bf16x8*>(&wb[(jj*4+ks)*512 + l*8]);
                    tt = __builtin_amdgcn_mfma_f32_16x16x32_bf16(ttf[ks], b, tt, 0, 0, 0);
                }
                if (t < 4) {
                    const int jx = 2*t + jj;
                    float bsc = sBias[384 + (jx<<4) + ln];
                    #pragma unroll
                    for (int r = 0; r < 4; ++r) accX[jx][r] *= (1.f + tt[r] + bsc);
                } else {
                    const int jx = 2*(t-4) + jj;
                    float bsh = sBias[256 + (jx<<4) + ln];
                    #pragma unroll
                    for (int r = 0; r < 4; ++r) accX[jx][r] += tt[r] + bsh;
                }
            }
        }
    }

    // ---- transpose inv -> A-layout, reusing idle Wb[1] (chunk 19 dead) ----
    short* tbW = &Wb[1][w * 1024];
    bf16x8 iaf[4];
    WAITL();                                 // own buf-1 ds_reads (t=7) retired
    BAR();                                   // all waves done with chunk 19
    #pragma unroll
    for (int hp = 0; hp < 2; ++hp) {
        #pragma unroll
        for (int nt4 = 0; nt4 < 4; ++nt4) {
            const int nt = hp*4 + nt4;
            #pragma unroll
            for (int r = 0; r < 4; ++r)
                tbW[tswz((lg<<2) + r, (nt4<<4) + ln)] = f2bf(accX[nt][r]);
        }
        #pragma unroll
        for (int k2 = 0; k2 < 2; ++k2)
            iaf[hp*2 + k2] = *reinterpret_cast<const bf16x8*>(&tbW[tswz(ln, (k2<<5) + kb)]);
    }
    WAITL();                                 // transpose reads done before stage(22)

    // ---- W1 stage: chunks 20..23 ----
    f32x4 accY[8];
    #pragma unroll
    for (int i = 0; i < 8; ++i) accY[i] = (f32x4){0.f,0.f,0.f,0.f};
    #pragma unroll
    for (int u = 0; u < 4; ++u) {
        if (u < 3) { WAITV(2); } else { WAITV(1); }
        BAR();
        if (u < 2)       { STAGE8(22 + u); } // chunks 22, 23
        else if (u == 2) { STAGEW2(); }      // chunk 24 (1 op/wave)
        {
            const short* wb = &Wb[(20 + u) % 3][0];
            #pragma unroll
            for (int s = 0; s < 2; ++s) {
                const int nt = 2*u + s;
                #pragma unroll
                for (int ks = 0; ks < 4; ++ks) {
                    bf16x8 b = *reinterpret_cast<const bf16x8*>(&wb[(s*4+ks)*512 + l*8]);
                    accY[nt] = __builtin_amdgcn_mfma_f32_16x16x32_bf16(iaf[ks], b, accY[nt], 0, 0, 0);
                }
            }
        }
    }

    // ---- silu + transpose back in Wb[1] (chunk 22 dead) ----
    bf16x8 yaf[4];
    WAITL();
    BAR();
    #pragma unroll
    for (int hp = 0; hp < 2; ++hp) {
        #pragma unroll
        for (int nt4 = 0; nt4 < 4; ++nt4) {
            const int nt = hp*4 + nt4;
            float bv = sBias[128 + (nt<<4) + ln];
            #pragma unroll
            for (int r = 0; r < 4; ++r)
                tbW[tswz((lg<<2) + r, (nt4<<4) + ln)] = f2bf(silu1(accY[nt][r] + bv));
        }
        #pragma unroll
        for (int k2 = 0; k2 < 2; ++k2)
            yaf[hp*2 + k2] = *reinterpret_cast<const bf16x8*>(&tbW[tswz(ln, (k2<<5) + kb)]);
    }

    // ---- W2 stage (chunk 24, buf 0) ----
    WAITV(0);
    BAR();
    f32x4 accZ = (f32x4){0.f,0.f,0.f,0.f};
    {
        const short* wb = &Wb[0][0];
        #pragma unroll
        for (int ks = 0; ks < 4; ++ks) {
            bf16x8 b = *reinterpret_cast<const bf16x8*>(&wb[ks*512 + l*8]);
            accZ = __builtin_amdgcn_mfma_f32_16x16x32_bf16(yaf[ks], b, accZ, 0, 0, 0);
        }
    }

    // ---- epilogue: geometry LOADED HERE + tanh + head-mean + atomic scatter ----
    {
        float dx = pos[ir*3+0] - pos[ic*3+0];
        float dy = pos[ir*3+1] - pos[ic*3+1];
        float dz = pos[ir*3+2] - pos[ic*3+2];
        float a0 = adj[em*3+0], a1 = adj[em*3+1], a2 = adj[em*3+2];
        float nrm = sqrtf(dx*dx + dy*dy + dz*dz);
        float sc  = cscale[0] / fmaxf(nrm, 1e-8f);
        float cdx = dx * sc, cdy = dy * sc, cdz = dz * sc;
        #pragma unroll
        for (int r = 0; r < 4; ++r) {
            const int m = (lg<<2) + r;       // edge within the wave tile
            float z  = tanh1(accZ[r]);
            float w0 = __shfl(a0, m), w1 = __shfl(a1, m), w2 = __shfl(a2, m);
            int   irm  = __shfl(ir, m);
            float cdxm = __shfl(cdx, m), cdym = __shfl(cdy, m), cdzm = __shfl(cdz, m);
            float wt = (ln == 0) ? 1.0f : (ln == 1 ? w0 : (ln == 2 ? w1 : (ln == 3 ? w2 : 0.0f)));
            float v = z * wt;
            v += __shfl_xor(v, 1);
            v += __shfl_xor(v, 2);           // heads 0..3 summed within 4-lane group
            float s = v * 0.25f;
            if (ln < 3) {
                float cdc = (ln == 0) ? cdxm : (ln == 1 ? cdym : cdzm);
                atomicAdd(&out[(long)irm*3 + ln], cdc * s);
            }
        }
    }
    #undef STAGE8
    #undef STAGEW2
}

extern "C" void kernel_launch(void* const* d_in, const int* in_sizes, int n_in,
                              void* d_out, int out_size, void* d_ws, size_t ws_size,
                              hipStream_t stream) {
    const float* h     = (const float*)d_in[0];
    const float* pos   = (const float*)d_in[1];
    const float* ea    = (const float*)d_in[2];
    const float* dist  = (const float*)d_in[3];
    const float* temb  = (const float*)d_in[4];
    const float* adj   = (const float*)d_in[5];
    const float* Wt    = (const float*)d_in[6];
    const float* bt    = (const float*)d_in[7];
    const float* Win   = (const float*)d_in[8];
    const float* bin   = (const float*)d_in[9];
    const float* W1    = (const float*)d_in[10];
    const float* b1    = (const float*)d_in[11];
    const float* W2    = (const float*)d_in[12];
    const float* cs    = (const float*)d_in[13];
    const int*   ei    = (const int*)d_in[14];
    float*       out   = (float*)d_out;
    short*       ws    = (short*)d_ws;

    const size_t W_SHORTS = 25 * 4096;                  // 102400
    const size_t H_SHORTS = (size_t)N_NODES * 128;      // 12.8M
    const bool   use_hbf  = ws_size >= (W_SHORTS + H_SHORTS) * sizeof(short);
    short*       hbf      = ws + W_SHORTS;

    pack_weights_kernel<<<(196*512 + 255) / 256, 256, 0, stream>>>(Wt, Win, W1, W2, ws);
    if (use_hbf)
        h_pack_kernel<<<(int)(H_SHORTS / 8 / 256), 256, 0, stream>>>(h, hbf);
    hipMemcpyAsync(out, pos, (size_t)out_size * sizeof(float),
                   hipMemcpyDeviceToDevice, stream);
    if (use_hbf)
        edge_kernel<true><<<E_EDGES / 64, 256, 0, stream>>>(h, hbf, pos, ea, dist, temb, adj,
                                                            bt, bin, b1, cs, ei, ws, out);
    else
        edge_kernel<false><<<E_EDGES / 64, 256, 0, stream>>>(h, hbf, pos, ea, dist, temb, adj,
                                                             bt, bin, b1, cs, ei, ws, out);
}